// Round 12
// baseline (942.393 us; speedup 1.0000x reference)
//
#include <hip/hip_runtime.h>
#include <hip/hip_fp16.h>

#define N_NODES 50000
#define N_EDGES 600000
#define IN_F 16
#define HF 128
#define NC 4
#define NHL 19
#define N_FP8_LAYERS 15  // hidden layers 0..14 have fp8 T; + input layer = 16 fp8 aggs
#define WS_STRIDE 136    // 128 f16 + 8 pad = 272 B rows

__device__ __forceinline__ float lrelu(float x) { return x > 0.f ? x : 0.01f * x; }

struct h4 { __half2 a, b; };  // 8 bytes = 4 fp16 feats

typedef _Float16 f16;
typedef _Float16 f16x8 __attribute__((ext_vector_type(8)));
typedef float    f32x4 __attribute__((ext_vector_type(4)));
typedef float    f32x2 __attribute__((ext_vector_type(2)));

__device__ __forceinline__ unsigned pack_fp8x4(float a, float b, float c, float d) {
    int r = __builtin_amdgcn_cvt_pk_fp8_f32(a, b, 0, false);
    r = __builtin_amdgcn_cvt_pk_fp8_f32(c, d, r, true);
    return (unsigned)r;
}

// ---------------- CSR build ----------------

__global__ void count_deg_k(const int* __restrict__ dst, int* __restrict__ cnt) {
    int e = blockIdx.x * 256 + threadIdx.x;
    if (e < N_EDGES) atomicAdd(&cnt[dst[e]], 1);
}

__global__ void deginv_k(const int* __restrict__ cnt, float* __restrict__ dinv) {
    int v = blockIdx.x * 256 + threadIdx.x;
    if (v < N_NODES) dinv[v] = 1.0f / fmaxf((float)cnt[v], 1.0f);
}

// single-block exclusive scan via wave shuffles: 4 elements/thread, 4096/chunk
__global__ void scan_k(const int* __restrict__ cnt, int* __restrict__ rowptr) {
    __shared__ int wsum[16];
    __shared__ int carry_s;
    int t = threadIdx.x;
    int lane = t & 63, wid = t >> 6;
    if (t == 0) carry_s = 0;
    __syncthreads();
    for (int base = 0; base < N_NODES; base += 4096) {
        int idx = base + t * 4;
        int4 v = make_int4(0, 0, 0, 0);
        if (idx + 3 < N_NODES) v = *(const int4*)&cnt[idx];
        else {
            if (idx     < N_NODES) v.x = cnt[idx];
            if (idx + 1 < N_NODES) v.y = cnt[idx + 1];
            if (idx + 2 < N_NODES) v.z = cnt[idx + 2];
            if (idx + 3 < N_NODES) v.w = cnt[idx + 3];
        }
        int s1 = v.x + v.y, s2 = s1 + v.z, total = s2 + v.w;
        int sc = total;
#pragma unroll
        for (int off = 1; off < 64; off <<= 1) {
            int u = __shfl_up(sc, off, 64);
            if (lane >= off) sc += u;
        }
        if (lane == 63) wsum[wid] = sc;
        __syncthreads();
        if (t < 16) {
            int w = wsum[t];
#pragma unroll
            for (int off = 1; off < 16; off <<= 1) {
                int u = __shfl_up(w, off, 64);
                if (t >= off) w += u;
            }
            wsum[t] = w;
        }
        __syncthreads();
        int prefix = carry_s + (wid > 0 ? wsum[wid - 1] : 0) + (sc - total);
        if (idx     < N_NODES) rowptr[idx]     = prefix;
        if (idx + 1 < N_NODES) rowptr[idx + 1] = prefix + v.x;
        if (idx + 2 < N_NODES) rowptr[idx + 2] = prefix + s1;
        if (idx + 3 < N_NODES) rowptr[idx + 3] = prefix + s2;
        __syncthreads();
        if (t == 0) carry_s += wsum[15];
        __syncthreads();
    }
    if (t == 0) rowptr[N_NODES] = carry_s;
}

// fill CSR: one int2 {src, bitcast(ea*dinv[dst])} store per edge
__global__ void fill_k(const int* __restrict__ src, const int* __restrict__ dst,
                       const float* __restrict__ ea, const int* __restrict__ rowptr,
                       int* __restrict__ fill, int2* __restrict__ edg,
                       const float* __restrict__ dinv) {
    int e = blockIdx.x * 256 + threadIdx.x;
    if (e < N_EDGES) {
        int d = dst[e];
        int pos = rowptr[d] + atomicAdd(&fill[d], 1);
        edg[pos] = make_int2(src[e], __float_as_int(ea[e] * dinv[d]));
    }
}

// ---------------- W convert: Wh[l][k][n] fp32 -> Wt[l][n][k] fp16 ----------------

__global__ void wconv_k(const float* __restrict__ Wh, __half* __restrict__ Wt) {
    int idx = blockIdx.x * 256 + threadIdx.x;
    if (idx >= NHL * HF * HF) return;
    int l = idx / (HF * HF);
    int r = idx - l * (HF * HF);
    int n = r >> 7;
    int k = r & 127;
    Wt[idx] = __float2half(Wh[(size_t)l * HF * HF + k * HF + n]);
}

// ---------------- input GEMM: T8[50000x128](fp8) = X[50000x16] @ W[16x128] + b ----------------

__global__ void gemm_in_k(const float* __restrict__ X, const float* __restrict__ W,
                          const float* __restrict__ b, unsigned* __restrict__ T8) {
    __shared__ float Ws[IN_F * HF];  // 8 KB
    int t = threadIdx.x;
    ((float4*)Ws)[t]       = ((const float4*)W)[t];
    ((float4*)Ws)[t + 256] = ((const float4*)W)[t + 256];
    __syncthreads();
    int row = blockIdx.x * 16 + (t >> 4);
    if (row >= N_NODES) return;
    int tx = t & 15;
    int c0 = tx * 4, c1 = 64 + tx * 4;
    float4 a0 = *(const float4*)&b[c0];
    float4 a1 = *(const float4*)&b[c1];
    const float4* xr = (const float4*)(X + row * IN_F);
#pragma unroll
    for (int k4 = 0; k4 < 4; k4++) {
        float4 xv = xr[k4];
        const float* xp = (const float*)&xv;
#pragma unroll
        for (int kk = 0; kk < 4; kk++) {
            int k = k4 * 4 + kk;
            float4 w0 = *(const float4*)&Ws[k * HF + c0];
            float4 w1 = *(const float4*)&Ws[k * HF + c1];
            float xs = xp[kk];
            a0.x = fmaf(xs, w0.x, a0.x); a0.y = fmaf(xs, w0.y, a0.y);
            a0.z = fmaf(xs, w0.z, a0.z); a0.w = fmaf(xs, w0.w, a0.w);
            a1.x = fmaf(xs, w1.x, a1.x); a1.y = fmaf(xs, w1.y, a1.y);
            a1.z = fmaf(xs, w1.z, a1.z); a1.w = fmaf(xs, w1.w, a1.w);
        }
    }
    T8[(size_t)row * 32 + tx]      = pack_fp8x4(a0.x, a0.y, a0.z, a0.w);
    T8[(size_t)row * 32 + 16 + tx] = pack_fp8x4(a1.x, a1.y, a1.z, a1.w);
}

// ---------------- hidden GEMM via MFMA f16: T = H @ W + b; T fp8 or fp16 ----------------
// H fp16 [M][128] staged in LDS; W fragments read DIRECTLY from global (32 KB, L2-hot).
// LDS = 17 KB -> high occupancy to hide H-staging latency.

template <bool FP8OUT>
__global__ __launch_bounds__(256, 4) void gemm_mfma_k(const __half* __restrict__ H,
                                                      const __half* __restrict__ Wt,
                                                      const float* __restrict__ b,
                                                      void* __restrict__ Tout) {
    __shared__ __half Hs[64 * WS_STRIDE];  // 17 KB, [row][k]; reused for C staging
    int t = threadIdx.x;
    int rbase = blockIdx.x * 64;
    int u16 = t & 15;
    int rg  = t >> 4;

#pragma unroll
    for (int p = 0; p < 4; p++) {
        int rl = p * 16 + rg;
        int row = rbase + rl;
        if (row >= N_NODES) row = N_NODES - 1;
        *(float4*)&Hs[rl * WS_STRIDE + u16 * 8] = *(const float4*)&H[(size_t)row * HF + u16 * 8];
    }
    __syncthreads();

    int lane = t & 63;
    int w    = t >> 6;
    int wr   = w * 16;
    int m16  = lane & 15;
    int q    = lane >> 4;

    f16x8 af[4];
#pragma unroll
    for (int kc = 0; kc < 4; kc++)
        af[kc] = *(const f16x8*)&Hs[(wr + m16) * WS_STRIDE + kc * 32 + q * 8];

    f32x4 acc[8];
#pragma unroll
    for (int nt = 0; nt < 8; nt++) {
        float bv = b[nt * 16 + m16];
        acc[nt] = (f32x4){bv, bv, bv, bv};
#pragma unroll
        for (int kc = 0; kc < 4; kc++) {
            f16x8 bf = *(const f16x8*)&Wt[(size_t)(nt * 16 + m16) * HF + kc * 32 + q * 8];
            acc[nt] = __builtin_amdgcn_mfma_f32_16x16x32_f16(af[kc], bf, acc[nt], 0, 0, 0);
        }
    }
    __syncthreads();  // done reading Hs; reuse for C staging [row][n] (fp16)

#pragma unroll
    for (int nt = 0; nt < 8; nt++)
#pragma unroll
        for (int r = 0; r < 4; r++)
            Hs[(wr + q * 4 + r) * WS_STRIDE + nt * 16 + m16] = __float2half(acc[nt][r]);
    __syncthreads();

#pragma unroll
    for (int p = 0; p < 4; p++) {
        int rl = p * 16 + rg;
        int row = rbase + rl;
        if (row < N_NODES) {
            float4 cv = *(float4*)&Hs[rl * WS_STRIDE + u16 * 8];  // 8 halves
            if (FP8OUT) {
                __half2* hp = (__half2*)&cv;
                float2 f0 = __half22float2(hp[0]);
                float2 f1 = __half22float2(hp[1]);
                float2 f2 = __half22float2(hp[2]);
                float2 f3 = __half22float2(hp[3]);
                uint2 o;
                o.x = pack_fp8x4(f0.x, f0.y, f1.x, f1.y);
                o.y = pack_fp8x4(f2.x, f2.y, f3.x, f3.y);
                *(uint2*)&((unsigned char*)Tout)[(size_t)row * HF + u16 * 8] = o;
            } else {
                *(float4*)&((__half*)Tout)[(size_t)row * HF + u16 * 8] = cv;
            }
        }
    }
}

// ---------------- aggregation: O(fp16) = lrelu(sum_e w_e * T[src_e]), T fp8 or fp16 ----
// TWO nodes per wave: lanes 0-31 = node vA (4 feats/lane), lanes 32-63 = node vB.

template <bool FP8IN>
__global__ __launch_bounds__(256) void agg2_k(const void* __restrict__ Tin,
                                              h4* __restrict__ O,
                                              const int* __restrict__ rowptr,
                                              const int2* __restrict__ edg) {
    int gw = blockIdx.x * 4 + (threadIdx.x >> 6);
    int vA = gw * 2;
    if (vA >= N_NODES) return;
    int lane = threadIdx.x & 63;
    int half = lane >> 5;
    int li   = lane & 31;

    int rA = __builtin_amdgcn_readfirstlane(rowptr[vA]);
    int rM = __builtin_amdgcn_readfirstlane(rowptr[vA + 1]);
    int rB = __builtin_amdgcn_readfirstlane(rowptr[vA + 2]);
    int eBase = half ? rM : rA;
    int eEnd  = half ? rB : rM;
    int degmax = max(rM - rA, rB - rM);
    int nb = (degmax + 15) >> 4;

    const h4*       T16 = (const h4*)Tin;
    const unsigned* T8  = (const unsigned*)Tin;

    float4 acc = make_float4(0.f, 0.f, 0.f, 0.f);

    for (int eb = 0; eb < nb; eb++) {
        int idx = eBase + eb * 16 + (li & 15);
        bool ok = idx < eEnd;
        int2 rec = edg[ok ? idx : 0];
        int   s_l = rec.x;
        float w_l = ok ? __int_as_float(rec.y) : 0.f;
        int sb = half << 5;
#pragma unroll
        for (int g = 0; g < 2; g++) {
            int   ss[8];
            float ww[8];
#pragma unroll
            for (int u = 0; u < 8; u++) {
                int sl = sb + g * 8 + u;
                ss[u] = __shfl(s_l, sl, 64);
                ww[u] = __shfl(w_l, sl, 64);
            }
            if (FP8IN) {
                unsigned gv[8];
#pragma unroll
                for (int u = 0; u < 8; u++)
                    gv[u] = T8[(size_t)ss[u] * 32 + li];
#pragma unroll
                for (int u = 0; u < 8; u++) {
                    f32x2 lo = __builtin_amdgcn_cvt_pk_f32_fp8((int)gv[u], false);
                    f32x2 hi = __builtin_amdgcn_cvt_pk_f32_fp8((int)gv[u], true);
                    acc.x = fmaf(lo.x, ww[u], acc.x);
                    acc.y = fmaf(lo.y, ww[u], acc.y);
                    acc.z = fmaf(hi.x, ww[u], acc.z);
                    acc.w = fmaf(hi.y, ww[u], acc.w);
                }
            } else {
                h4 hv[8];
#pragma unroll
                for (int u = 0; u < 8; u++)
                    hv[u] = T16[(size_t)ss[u] * (HF / 4) + li];
#pragma unroll
                for (int u = 0; u < 8; u++) {
                    float2 p0 = __half22float2(hv[u].a);
                    float2 p1 = __half22float2(hv[u].b);
                    acc.x = fmaf(p0.x, ww[u], acc.x);
                    acc.y = fmaf(p0.y, ww[u], acc.y);
                    acc.z = fmaf(p1.x, ww[u], acc.z);
                    acc.w = fmaf(p1.y, ww[u], acc.w);
                }
            }
        }
    }
    int v = vA + half;
    h4 o;
    o.a = __floats2half2_rn(lrelu(acc.x), lrelu(acc.y));
    o.b = __floats2half2_rn(lrelu(acc.z), lrelu(acc.w));
    O[(size_t)v * (HF / 4) + li] = o;
}

// ---------------- output layer: out = H(fp16) @ Wfc + bfc (N=4) ----------------

__global__ void fc_k(const __half* __restrict__ H, const float* __restrict__ W,
                     const float* __restrict__ b, float* __restrict__ out) {
    int r = blockIdx.x * 256 + threadIdx.x;
    if (r >= N_NODES) return;
    float4 acc = *(const float4*)b;
    const h4* hp = (const h4*)(H + (size_t)r * HF);
    const float4* w4 = (const float4*)W;
#pragma unroll
    for (int k4 = 0; k4 < 32; k4++) {
        h4 hh = hp[k4];
        float2 p0 = __half22float2(hh.a);
        float2 p1 = __half22float2(hh.b);
        float4 wa = w4[k4 * 4 + 0], wb = w4[k4 * 4 + 1];
        float4 wc = w4[k4 * 4 + 2], wd = w4[k4 * 4 + 3];
        acc.x = fmaf(p0.x, wa.x, acc.x); acc.y = fmaf(p0.x, wa.y, acc.y);
        acc.z = fmaf(p0.x, wa.z, acc.z); acc.w = fmaf(p0.x, wa.w, acc.w);
        acc.x = fmaf(p0.y, wb.x, acc.x); acc.y = fmaf(p0.y, wb.y, acc.y);
        acc.z = fmaf(p0.y, wb.z, acc.z); acc.w = fmaf(p0.y, wb.w, acc.w);
        acc.x = fmaf(p1.x, wc.x, acc.x); acc.y = fmaf(p1.x, wc.y, acc.y);
        acc.z = fmaf(p1.x, wc.z, acc.z); acc.w = fmaf(p1.x, wc.w, acc.w);
        acc.x = fmaf(p1.y, wd.x, acc.x); acc.y = fmaf(p1.y, wd.y, acc.y);
        acc.z = fmaf(p1.y, wd.z, acc.z); acc.w = fmaf(p1.y, wd.w, acc.w);
    }
    *(float4*)&out[r * NC] = acc;
}

// ---------------- driver ----------------

extern "C" void kernel_launch(void* const* d_in, const int* in_sizes, int n_in,
                              void* d_out, int out_size, void* d_ws, size_t ws_size,
                              hipStream_t stream) {
    const float* X   = (const float*)d_in[0];
    const int*   EI  = (const int*)d_in[1];
    const float* EA  = (const float*)d_in[2];
    const float* Win = (const float*)d_in[3];
    const float* bin = (const float*)d_in[4];
    const float* Wh  = (const float*)d_in[5];
    const float* bh  = (const float*)d_in[6];
    const float* Wfc = (const float*)d_in[7];
    const float* bfc = (const float*)d_in[8];
    float* out = (float*)d_out;
    const int* src = EI;
    const int* dst = EI + N_EDGES;

    char* ws = (char*)d_ws;
    size_t off = 0;
    __half* Oh  = (__half*)(ws + off); off += (size_t)N_NODES * HF * 2;   // 12.8 MB
    void*   T   = (void*)(ws + off);   off += (size_t)N_NODES * HF * 2;   // 12.8 MB (fp16) / 6.4 (fp8)
    __half* Wt  = (__half*)(ws + off); off += (size_t)NHL * HF * HF * 2;  // 623 KB
    int2* edg   = (int2*)(ws + off);  off += (size_t)N_EDGES * 8;
    int* rowptr = (int*)(ws + off);   off += (((size_t)(N_NODES + 1) * 4 + 15) / 16) * 16;
    int* cnt    = (int*)(ws + off);   off += (size_t)N_NODES * 4;
    int* fill   = (int*)(ws + off);   off += (size_t)N_NODES * 4;
    float* dinv = (float*)(ws + off); off += (size_t)N_NODES * 4;

    hipMemsetAsync(cnt, 0, N_NODES * 4, stream);
    hipMemsetAsync(fill, 0, N_NODES * 4, stream);
    count_deg_k<<<(N_EDGES + 255) / 256, 256, 0, stream>>>(dst, cnt);
    deginv_k<<<(N_NODES + 255) / 256, 256, 0, stream>>>(cnt, dinv);
    scan_k<<<1, 1024, 0, stream>>>(cnt, rowptr);
    fill_k<<<(N_EDGES + 255) / 256, 256, 0, stream>>>(src, dst, EA, rowptr, fill, edg, dinv);
    wconv_k<<<(NHL * HF * HF + 255) / 256, 256, 0, stream>>>(Wh, Wt);

    const int aggg  = (N_NODES / 2 + 3) / 4;
    const int gemmg = (N_NODES + 63) / 64;

    // input layer: fp8 T (max distance from output — error fully damped)
    gemm_in_k<<<(N_NODES + 15) / 16, 256, 0, stream>>>(X, Win, bin, (unsigned*)T);
    agg2_k<true><<<aggg, 256, 0, stream>>>(T, (h4*)Oh, rowptr, edg);
    // hidden layers 0..N_FP8_LAYERS-1: fp8 T
    for (int l = 0; l < N_FP8_LAYERS; l++) {
        gemm_mfma_k<true><<<gemmg, 256, 0, stream>>>(
            Oh, Wt + (size_t)l * HF * HF, bh + (size_t)l * HF, T);
        agg2_k<true><<<aggg, 256, 0, stream>>>(T, (h4*)Oh, rowptr, edg);
    }
    // remaining hidden layers: fp16 T (protect output precision)
    for (int l = N_FP8_LAYERS; l < NHL; l++) {
        gemm_mfma_k<false><<<gemmg, 256, 0, stream>>>(
            Oh, Wt + (size_t)l * HF * HF, bh + (size_t)l * HF, T);
        agg2_k<false><<<aggg, 256, 0, stream>>>(T, (h4*)Oh, rowptr, edg);
    }
    fc_k<<<(N_NODES + 255) / 256, 256, 0, stream>>>(Oh, Wfc, bfc, out);
}

// Round 13
// 713.654 us; speedup vs baseline: 1.3205x; 1.3205x over previous
//
#include <hip/hip_runtime.h>
#include <hip/hip_fp16.h>

#define N_NODES 50000
#define N_EDGES 600000
#define IN_F 16
#define HF 128
#define NC 4
#define NHL 19
#define N_FP8_LAYERS 15  // hidden layers 0..14 have fp8 T; + input layer = 16 fp8 aggs
#define WS_STRIDE 136    // 128 f16 + 8 pad = 272 B rows

__device__ __forceinline__ float lrelu(float x) { return x > 0.f ? x : 0.01f * x; }

struct h4 { __half2 a, b; };  // 8 bytes = 4 fp16 feats

typedef _Float16 f16;
typedef _Float16 f16x8 __attribute__((ext_vector_type(8)));
typedef float    f32x4 __attribute__((ext_vector_type(4)));
typedef float    f32x2 __attribute__((ext_vector_type(2)));

__device__ __forceinline__ unsigned pack_fp8x4(float a, float b, float c, float d) {
    int r = __builtin_amdgcn_cvt_pk_fp8_f32(a, b, 0, false);
    r = __builtin_amdgcn_cvt_pk_fp8_f32(c, d, r, true);
    return (unsigned)r;
}

// ---------------- CSR build ----------------

__global__ void count_deg_k(const int* __restrict__ dst, int* __restrict__ cnt) {
    int e = blockIdx.x * 256 + threadIdx.x;
    if (e < N_EDGES) atomicAdd(&cnt[dst[e]], 1);
}

__global__ void deginv_k(const int* __restrict__ cnt, float* __restrict__ dinv) {
    int v = blockIdx.x * 256 + threadIdx.x;
    if (v < N_NODES) dinv[v] = 1.0f / fmaxf((float)cnt[v], 1.0f);
}

// single-block exclusive scan via wave shuffles: 4 elements/thread, 4096/chunk
__global__ void scan_k(const int* __restrict__ cnt, int* __restrict__ rowptr) {
    __shared__ int wsum[16];
    __shared__ int carry_s;
    int t = threadIdx.x;
    int lane = t & 63, wid = t >> 6;
    if (t == 0) carry_s = 0;
    __syncthreads();
    for (int base = 0; base < N_NODES; base += 4096) {
        int idx = base + t * 4;
        int4 v = make_int4(0, 0, 0, 0);
        if (idx + 3 < N_NODES) v = *(const int4*)&cnt[idx];
        else {
            if (idx     < N_NODES) v.x = cnt[idx];
            if (idx + 1 < N_NODES) v.y = cnt[idx + 1];
            if (idx + 2 < N_NODES) v.z = cnt[idx + 2];
            if (idx + 3 < N_NODES) v.w = cnt[idx + 3];
        }
        int s1 = v.x + v.y, s2 = s1 + v.z, total = s2 + v.w;
        int sc = total;
#pragma unroll
        for (int off = 1; off < 64; off <<= 1) {
            int u = __shfl_up(sc, off, 64);
            if (lane >= off) sc += u;
        }
        if (lane == 63) wsum[wid] = sc;
        __syncthreads();
        if (t < 16) {
            int w = wsum[t];
#pragma unroll
            for (int off = 1; off < 16; off <<= 1) {
                int u = __shfl_up(w, off, 64);
                if (t >= off) w += u;
            }
            wsum[t] = w;
        }
        __syncthreads();
        int prefix = carry_s + (wid > 0 ? wsum[wid - 1] : 0) + (sc - total);
        if (idx     < N_NODES) rowptr[idx]     = prefix;
        if (idx + 1 < N_NODES) rowptr[idx + 1] = prefix + v.x;
        if (idx + 2 < N_NODES) rowptr[idx + 2] = prefix + s1;
        if (idx + 3 < N_NODES) rowptr[idx + 3] = prefix + s2;
        __syncthreads();
        if (t == 0) carry_s += wsum[15];
        __syncthreads();
    }
    if (t == 0) rowptr[N_NODES] = carry_s;
}

// fill CSR: one int2 {src, bitcast(ea*dinv[dst])} store per edge
__global__ void fill_k(const int* __restrict__ src, const int* __restrict__ dst,
                       const float* __restrict__ ea, const int* __restrict__ rowptr,
                       int* __restrict__ fill, int2* __restrict__ edg,
                       const float* __restrict__ dinv) {
    int e = blockIdx.x * 256 + threadIdx.x;
    if (e < N_EDGES) {
        int d = dst[e];
        int pos = rowptr[d] + atomicAdd(&fill[d], 1);
        edg[pos] = make_int2(src[e], __float_as_int(ea[e] * dinv[d]));
    }
}

// ---------------- W convert: Wh[l][k][n] fp32 -> Wt[l][n][k] fp16 ----------------

__global__ void wconv_k(const float* __restrict__ Wh, __half* __restrict__ Wt) {
    int idx = blockIdx.x * 256 + threadIdx.x;
    if (idx >= NHL * HF * HF) return;
    int l = idx / (HF * HF);
    int r = idx - l * (HF * HF);
    int n = r >> 7;
    int k = r & 127;
    Wt[idx] = __float2half(Wh[(size_t)l * HF * HF + k * HF + n]);
}

// ---------------- input GEMM: T8[50000x128](fp8) = X[50000x16] @ W[16x128] + b ----------------

__global__ void gemm_in_k(const float* __restrict__ X, const float* __restrict__ W,
                          const float* __restrict__ b, unsigned* __restrict__ T8) {
    __shared__ float Ws[IN_F * HF];  // 8 KB
    int t = threadIdx.x;
    ((float4*)Ws)[t]       = ((const float4*)W)[t];
    ((float4*)Ws)[t + 256] = ((const float4*)W)[t + 256];
    __syncthreads();
    int row = blockIdx.x * 16 + (t >> 4);
    if (row >= N_NODES) return;
    int tx = t & 15;
    int c0 = tx * 4, c1 = 64 + tx * 4;
    float4 a0 = *(const float4*)&b[c0];
    float4 a1 = *(const float4*)&b[c1];
    const float4* xr = (const float4*)(X + row * IN_F);
#pragma unroll
    for (int k4 = 0; k4 < 4; k4++) {
        float4 xv = xr[k4];
        const float* xp = (const float*)&xv;
#pragma unroll
        for (int kk = 0; kk < 4; kk++) {
            int k = k4 * 4 + kk;
            float4 w0 = *(const float4*)&Ws[k * HF + c0];
            float4 w1 = *(const float4*)&Ws[k * HF + c1];
            float xs = xp[kk];
            a0.x = fmaf(xs, w0.x, a0.x); a0.y = fmaf(xs, w0.y, a0.y);
            a0.z = fmaf(xs, w0.z, a0.z); a0.w = fmaf(xs, w0.w, a0.w);
            a1.x = fmaf(xs, w1.x, a1.x); a1.y = fmaf(xs, w1.y, a1.y);
            a1.z = fmaf(xs, w1.z, a1.z); a1.w = fmaf(xs, w1.w, a1.w);
        }
    }
    T8[(size_t)row * 32 + tx]      = pack_fp8x4(a0.x, a0.y, a0.z, a0.w);
    T8[(size_t)row * 32 + 16 + tx] = pack_fp8x4(a1.x, a1.y, a1.z, a1.w);
}

// ---------------- hidden GEMM via MFMA f16: T = H @ W + b; T fp8 or fp16 ----------------
// R11 form: W tile + H tile both staged in LDS (51 KB). W-from-global was tried in R12
// and cost +10 us/gemm (strided fragment loads + VGPR spills) — do not repeat.

template <bool FP8OUT>
__global__ __launch_bounds__(256) void gemm_mfma_k(const __half* __restrict__ H,
                                                   const __half* __restrict__ Wt,
                                                   const float* __restrict__ b,
                                                   void* __restrict__ Tout) {
    __shared__ __half Ws[HF * WS_STRIDE];  // 34 KB, [n][k]
    __shared__ __half Hs[64 * WS_STRIDE];  // 17 KB, [row][k]; reused for C staging
    int t = threadIdx.x;
    int rbase = blockIdx.x * 64;
    int u16 = t & 15;
    int rg  = t >> 4;

#pragma unroll
    for (int p = 0; p < 8; p++) {
        int n = p * 16 + rg;
        *(float4*)&Ws[n * WS_STRIDE + u16 * 8] = *(const float4*)&Wt[(size_t)n * HF + u16 * 8];
    }
#pragma unroll
    for (int p = 0; p < 4; p++) {
        int rl = p * 16 + rg;
        int row = rbase + rl;
        if (row >= N_NODES) row = N_NODES - 1;
        *(float4*)&Hs[rl * WS_STRIDE + u16 * 8] = *(const float4*)&H[(size_t)row * HF + u16 * 8];
    }
    __syncthreads();

    int lane = t & 63;
    int w    = t >> 6;
    int wr   = w * 16;
    int m16  = lane & 15;
    int q    = lane >> 4;

    f16x8 af[4];
#pragma unroll
    for (int kc = 0; kc < 4; kc++)
        af[kc] = *(const f16x8*)&Hs[(wr + m16) * WS_STRIDE + kc * 32 + q * 8];

    f32x4 acc[8];
#pragma unroll
    for (int nt = 0; nt < 8; nt++) {
        float bv = b[nt * 16 + m16];
        acc[nt] = (f32x4){bv, bv, bv, bv};
#pragma unroll
        for (int kc = 0; kc < 4; kc++) {
            f16x8 bf = *(const f16x8*)&Ws[(nt * 16 + m16) * WS_STRIDE + kc * 32 + q * 8];
            acc[nt] = __builtin_amdgcn_mfma_f32_16x16x32_f16(af[kc], bf, acc[nt], 0, 0, 0);
        }
    }
    __syncthreads();  // done reading Hs; reuse for C staging [row][n] (fp16)

#pragma unroll
    for (int nt = 0; nt < 8; nt++)
#pragma unroll
        for (int r = 0; r < 4; r++)
            Hs[(wr + q * 4 + r) * WS_STRIDE + nt * 16 + m16] = __float2half(acc[nt][r]);
    __syncthreads();

#pragma unroll
    for (int p = 0; p < 4; p++) {
        int rl = p * 16 + rg;
        int row = rbase + rl;
        if (row < N_NODES) {
            float4 cv = *(float4*)&Hs[rl * WS_STRIDE + u16 * 8];  // 8 halves
            if (FP8OUT) {
                __half2* hp = (__half2*)&cv;
                float2 f0 = __half22float2(hp[0]);
                float2 f1 = __half22float2(hp[1]);
                float2 f2 = __half22float2(hp[2]);
                float2 f3 = __half22float2(hp[3]);
                uint2 o;
                o.x = pack_fp8x4(f0.x, f0.y, f1.x, f1.y);
                o.y = pack_fp8x4(f2.x, f2.y, f3.x, f3.y);
                *(uint2*)&((unsigned char*)Tout)[(size_t)row * HF + u16 * 8] = o;
            } else {
                *(float4*)&((__half*)Tout)[(size_t)row * HF + u16 * 8] = cv;
            }
        }
    }
}

// ---------------- aggregation: O(fp16) = lrelu(sum_e w_e * T[src_e]), T fp8 or fp16 ----
// TWO nodes per wave: lanes 0-31 = node vA (4 feats/lane), lanes 32-63 = node vB.

template <bool FP8IN>
__global__ __launch_bounds__(256) void agg2_k(const void* __restrict__ Tin,
                                              h4* __restrict__ O,
                                              const int* __restrict__ rowptr,
                                              const int2* __restrict__ edg) {
    int gw = blockIdx.x * 4 + (threadIdx.x >> 6);
    int vA = gw * 2;
    if (vA >= N_NODES) return;
    int lane = threadIdx.x & 63;
    int half = lane >> 5;
    int li   = lane & 31;

    int rA = __builtin_amdgcn_readfirstlane(rowptr[vA]);
    int rM = __builtin_amdgcn_readfirstlane(rowptr[vA + 1]);
    int rB = __builtin_amdgcn_readfirstlane(rowptr[vA + 2]);
    int eBase = half ? rM : rA;
    int eEnd  = half ? rB : rM;
    int degmax = max(rM - rA, rB - rM);
    int nb = (degmax + 15) >> 4;

    const h4*       T16 = (const h4*)Tin;
    const unsigned* T8  = (const unsigned*)Tin;

    float4 acc = make_float4(0.f, 0.f, 0.f, 0.f);

    for (int eb = 0; eb < nb; eb++) {
        int idx = eBase + eb * 16 + (li & 15);
        bool ok = idx < eEnd;
        int2 rec = edg[ok ? idx : 0];
        int   s_l = rec.x;
        float w_l = ok ? __int_as_float(rec.y) : 0.f;
        int sb = half << 5;
#pragma unroll
        for (int g = 0; g < 2; g++) {
            int   ss[8];
            float ww[8];
#pragma unroll
            for (int u = 0; u < 8; u++) {
                int sl = sb + g * 8 + u;
                ss[u] = __shfl(s_l, sl, 64);
                ww[u] = __shfl(w_l, sl, 64);
            }
            if (FP8IN) {
                unsigned gv[8];
#pragma unroll
                for (int u = 0; u < 8; u++)
                    gv[u] = T8[(size_t)ss[u] * 32 + li];
#pragma unroll
                for (int u = 0; u < 8; u++) {
                    f32x2 lo = __builtin_amdgcn_cvt_pk_f32_fp8((int)gv[u], false);
                    f32x2 hi = __builtin_amdgcn_cvt_pk_f32_fp8((int)gv[u], true);
                    acc.x = fmaf(lo.x, ww[u], acc.x);
                    acc.y = fmaf(lo.y, ww[u], acc.y);
                    acc.z = fmaf(hi.x, ww[u], acc.z);
                    acc.w = fmaf(hi.y, ww[u], acc.w);
                }
            } else {
                h4 hv[8];
#pragma unroll
                for (int u = 0; u < 8; u++)
                    hv[u] = T16[(size_t)ss[u] * (HF / 4) + li];
#pragma unroll
                for (int u = 0; u < 8; u++) {
                    float2 p0 = __half22float2(hv[u].a);
                    float2 p1 = __half22float2(hv[u].b);
                    acc.x = fmaf(p0.x, ww[u], acc.x);
                    acc.y = fmaf(p0.y, ww[u], acc.y);
                    acc.z = fmaf(p1.x, ww[u], acc.z);
                    acc.w = fmaf(p1.y, ww[u], acc.w);
                }
            }
        }
    }
    int v = vA + half;
    h4 o;
    o.a = __floats2half2_rn(lrelu(acc.x), lrelu(acc.y));
    o.b = __floats2half2_rn(lrelu(acc.z), lrelu(acc.w));
    O[(size_t)v * (HF / 4) + li] = o;
}

// ---------------- output layer: out = H(fp16) @ Wfc + bfc (N=4) ----------------

__global__ void fc_k(const __half* __restrict__ H, const float* __restrict__ W,
                     const float* __restrict__ b, float* __restrict__ out) {
    int r = blockIdx.x * 256 + threadIdx.x;
    if (r >= N_NODES) return;
    float4 acc = *(const float4*)b;
    const h4* hp = (const h4*)(H + (size_t)r * HF);
    const float4* w4 = (const float4*)W;
#pragma unroll
    for (int k4 = 0; k4 < 32; k4++) {
        h4 hh = hp[k4];
        float2 p0 = __half22float2(hh.a);
        float2 p1 = __half22float2(hh.b);
        float4 wa = w4[k4 * 4 + 0], wb = w4[k4 * 4 + 1];
        float4 wc = w4[k4 * 4 + 2], wd = w4[k4 * 4 + 3];
        acc.x = fmaf(p0.x, wa.x, acc.x); acc.y = fmaf(p0.x, wa.y, acc.y);
        acc.z = fmaf(p0.x, wa.z, acc.z); acc.w = fmaf(p0.x, wa.w, acc.w);
        acc.x = fmaf(p0.y, wb.x, acc.x); acc.y = fmaf(p0.y, wb.y, acc.y);
        acc.z = fmaf(p0.y, wb.z, acc.z); acc.w = fmaf(p0.y, wb.w, acc.w);
        acc.x = fmaf(p1.x, wc.x, acc.x); acc.y = fmaf(p1.x, wc.y, acc.y);
        acc.z = fmaf(p1.x, wc.z, acc.z); acc.w = fmaf(p1.x, wc.w, acc.w);
        acc.x = fmaf(p1.y, wd.x, acc.x); acc.y = fmaf(p1.y, wd.y, acc.y);
        acc.z = fmaf(p1.y, wd.z, acc.z); acc.w = fmaf(p1.y, wd.w, acc.w);
    }
    *(float4*)&out[r * NC] = acc;
}

// ---------------- driver ----------------

extern "C" void kernel_launch(void* const* d_in, const int* in_sizes, int n_in,
                              void* d_out, int out_size, void* d_ws, size_t ws_size,
                              hipStream_t stream) {
    const float* X   = (const float*)d_in[0];
    const int*   EI  = (const int*)d_in[1];
    const float* EA  = (const float*)d_in[2];
    const float* Win = (const float*)d_in[3];
    const float* bin = (const float*)d_in[4];
    const float* Wh  = (const float*)d_in[5];
    const float* bh  = (const float*)d_in[6];
    const float* Wfc = (const float*)d_in[7];
    const float* bfc = (const float*)d_in[8];
    float* out = (float*)d_out;
    const int* src = EI;
    const int* dst = EI + N_EDGES;

    char* ws = (char*)d_ws;
    size_t off = 0;
    __half* Oh  = (__half*)(ws + off); off += (size_t)N_NODES * HF * 2;   // 12.8 MB
    void*   T   = (void*)(ws + off);   off += (size_t)N_NODES * HF * 2;   // 12.8 MB (fp16) / 6.4 (fp8)
    __half* Wt  = (__half*)(ws + off); off += (size_t)NHL * HF * HF * 2;  // 623 KB
    int2* edg   = (int2*)(ws + off);  off += (size_t)N_EDGES * 8;
    int* rowptr = (int*)(ws + off);   off += (((size_t)(N_NODES + 1) * 4 + 15) / 16) * 16;
    int* cnt    = (int*)(ws + off);   off += (size_t)N_NODES * 4;
    int* fill   = (int*)(ws + off);   off += (size_t)N_NODES * 4;
    float* dinv = (float*)(ws + off); off += (size_t)N_NODES * 4;

    hipMemsetAsync(cnt, 0, N_NODES * 4, stream);
    hipMemsetAsync(fill, 0, N_NODES * 4, stream);
    count_deg_k<<<(N_EDGES + 255) / 256, 256, 0, stream>>>(dst, cnt);
    deginv_k<<<(N_NODES + 255) / 256, 256, 0, stream>>>(cnt, dinv);
    scan_k<<<1, 1024, 0, stream>>>(cnt, rowptr);
    fill_k<<<(N_EDGES + 255) / 256, 256, 0, stream>>>(src, dst, EA, rowptr, fill, edg, dinv);
    wconv_k<<<(NHL * HF * HF + 255) / 256, 256, 0, stream>>>(Wh, Wt);

    const int aggg  = (N_NODES / 2 + 3) / 4;
    const int gemmg = (N_NODES + 63) / 64;

    // input layer: fp8 T (max distance from output — error fully damped)
    gemm_in_k<<<(N_NODES + 15) / 16, 256, 0, stream>>>(X, Win, bin, (unsigned*)T);
    agg2_k<true><<<aggg, 256, 0, stream>>>(T, (h4*)Oh, rowptr, edg);
    // hidden layers 0..N_FP8_LAYERS-1: fp8 T
    for (int l = 0; l < N_FP8_LAYERS; l++) {
        gemm_mfma_k<true><<<gemmg, 256, 0, stream>>>(
            Oh, Wt + (size_t)l * HF * HF, bh + (size_t)l * HF, T);
        agg2_k<true><<<aggg, 256, 0, stream>>>(T, (h4*)Oh, rowptr, edg);
    }
    // remaining hidden layers: fp16 T (protect output precision)
    for (int l = N_FP8_LAYERS; l < NHL; l++) {
        gemm_mfma_k<false><<<gemmg, 256, 0, stream>>>(
            Oh, Wt + (size_t)l * HF * HF, bh + (size_t)l * HF, T);
        agg2_k<false><<<aggg, 256, 0, stream>>>(T, (h4*)Oh, rowptr, edg);
    }
    fc_k<<<(N_NODES + 255) / 256, 256, 0, stream>>>(Oh, Wfc, bfc, out);
}